// Round 1
// baseline (870.285 us; speedup 1.0000x reference)
//
#include <hip/hip_runtime.h>
#include <cstdint>
#include <cstddef>

#define T_TOK 2048
#define DHID  2048
#define NEXP  8
#define FMOE  1408
#define FSH   2816
#define CAP   5120   // 4096 slots + 8*128 per-expert padding

typedef short short8 __attribute__((ext_vector_type(8)));
typedef float f32x4  __attribute__((ext_vector_type(4)));

__device__ __forceinline__ float bf2f(short s) {
  unsigned u = ((unsigned)(unsigned short)s) << 16;
  return __builtin_bit_cast(float, u);
}
__device__ __forceinline__ short f2bf(float f) {
  unsigned u = __builtin_bit_cast(unsigned, f);
  u += 0x7fffu + ((u >> 16) & 1u);
  return (short)(u >> 16);
}
__device__ __forceinline__ short8 cvt8(float4 a, float4 b) {
  short8 r;
  r[0]=f2bf(a.x); r[1]=f2bf(a.y); r[2]=f2bf(a.z); r[3]=f2bf(a.w);
  r[4]=f2bf(b.x); r[5]=f2bf(b.y); r[6]=f2bf(b.z); r[7]=f2bf(b.w);
  return r;
}

// ---- gating: fp32 scores, sigmoid, top-2, counts; also write x as bf16 ----
__global__ void k_gate(const float* __restrict__ x, const float* __restrict__ gw,
                       int* __restrict__ top_idx, float* __restrict__ top_w,
                       int* __restrict__ ctrl, short* __restrict__ x16)
{
  int t = blockIdx.x, tid = threadIdx.x;
  const float* xr = x + (size_t)t * DHID + tid * 8;
  float4 v0 = *(const float4*)xr;
  float4 v1 = *(const float4*)(xr + 4);
  short8 xv = cvt8(v0, v1);
  *(short8*)(x16 + (size_t)t * DHID + tid * 8) = xv;

  float s[NEXP];
  #pragma unroll
  for (int e = 0; e < NEXP; e++) {
    const float* gr = gw + e * DHID + tid * 8;
    float4 g0 = *(const float4*)gr;
    float4 g1 = *(const float4*)(gr + 4);
    s[e] = v0.x*g0.x + v0.y*g0.y + v0.z*g0.z + v0.w*g0.w
         + v1.x*g1.x + v1.y*g1.y + v1.z*g1.z + v1.w*g1.w;
  }
  #pragma unroll
  for (int e = 0; e < NEXP; e++)
    #pragma unroll
    for (int off = 32; off > 0; off >>= 1)
      s[e] += __shfl_xor(s[e], off);

  __shared__ float red[4][NEXP];
  int lane = tid & 63, wave = tid >> 6;
  if (lane == 0)
    for (int e = 0; e < NEXP; e++) red[wave][e] = s[e];
  __syncthreads();

  if (tid == 0) {
    float sc[NEXP];
    for (int e = 0; e < NEXP; e++) {
      float v = red[0][e] + red[1][e] + red[2][e] + red[3][e];
      sc[e] = 1.f / (1.f + __expf(-v));
    }
    int i0 = 0; float s0 = sc[0];
    for (int e = 1; e < NEXP; e++) if (sc[e] > s0) { s0 = sc[e]; i0 = e; }
    int i1 = -1; float s1 = -1e30f;
    for (int e = 0; e < NEXP; e++) if (e != i0 && sc[e] > s1) { s1 = sc[e]; i1 = e; }
    float inv = 2.5f / (s0 + s1 + 1e-20f);
    top_idx[2*t] = i0; top_idx[2*t+1] = i1;
    top_w[2*t] = s0 * inv; top_w[2*t+1] = s1 * inv;
    atomicAdd(&ctrl[i0], 1);
    atomicAdd(&ctrl[i1], 1);
  }
}

// ---- per-expert offsets, 128-row padded regions ----
__global__ void k_offsets(int* __restrict__ ctrl)
{
  if (blockIdx.x == 0 && threadIdx.x == 0) {
    int cum = 0;
    for (int e = 0; e < NEXP; e++) {
      ctrl[16 + e] = cum;
      cum += (ctrl[e] + 127) & ~127;
    }
  }
}

// ---- gather token rows into compact per-expert matrix Xg ----
__global__ void k_gather(const short* __restrict__ x16, const int* __restrict__ top_idx,
                         int* __restrict__ ctrl, int* __restrict__ tok_row,
                         short* __restrict__ Xg)
{
  int t = blockIdx.x, tid = threadIdx.x;
  __shared__ int rows[2];
  if (tid < 2) {
    int e = top_idx[2*t + tid];
    int slot = atomicAdd(&ctrl[8 + e], 1);
    int row = ctrl[16 + e] + slot;
    rows[tid] = row;
    tok_row[2*t + tid] = row;
  }
  __syncthreads();
  uint4 v = *(const uint4*)(x16 + (size_t)t * DHID + tid * 8);
  *(uint4*)(Xg + (size_t)rows[0] * DHID + tid * 8) = v;
  *(uint4*)(Xg + (size_t)rows[1] * DHID + tid * 8) = v;
}

// ---- 128x128x32 bf16 MFMA GEMM, C[M,N] = A[M,K] @ W[N,K]^T ----
// A bf16 row-major stride K; W fp32 row-major stride K (converted to bf16 at stage).
// EXPERT: blockIdx.z encodes expert (and DUAL selects B0/B1,C0/C1); rows indirect
// via ctrl offsets with early-exit on count.
template<bool EXPERT, bool DUAL, bool OUT_BF16>
__global__ __launch_bounds__(256) void k_gemm(
    const short* __restrict__ A, const float* __restrict__ B0,
    const float* __restrict__ B1, void* __restrict__ C0v, void* __restrict__ C1v,
    int N, int K, const int* __restrict__ ctrl)
{
  int m0 = blockIdx.y * 128;
  const float* Bw;
  void* Cv;
  if (DUAL) { int j = blockIdx.z & 1; Bw = j ? B1 : B0; Cv = j ? C1v : C0v; }
  else      { Bw = B0; Cv = C0v; }
  if (EXPERT) {
    int e = DUAL ? (int)(blockIdx.z >> 1) : (int)blockIdx.z;
    if (m0 >= ctrl[e]) return;          // beyond this expert's token count
    m0 += ctrl[16 + e];                 // region base row
    Bw += (size_t)e * N * K;
  }
  int n0 = blockIdx.x * 128;

  __shared__ short As[128 * 32];
  __shared__ short Bs[128 * 32];

  int tid = threadIdx.x;
  int lane = tid & 63, wave = tid >> 6;
  int l15 = lane & 15, q = lane >> 4;
  int wm = (wave >> 1) * 64, wn = (wave & 1) * 64;

  f32x4 z4 = {0.f, 0.f, 0.f, 0.f};
  f32x4 acc[4][4];
  #pragma unroll
  for (int a = 0; a < 4; a++)
    #pragma unroll
    for (int b = 0; b < 4; b++) acc[a][b] = z4;

  // staging map: chunk c in [0,512) covers LDS bytes [c*16, c*16+16),
  // i.e. tile row c>>2, k-subchunk c&3 (8 elems). Thread handles c=tid, tid+256.
  const short* Ag = A + (size_t)(m0 + (tid >> 2)) * K + (tid & 3) * 8;
  const float* Bg = Bw + (size_t)(n0 + (tid >> 2)) * K + (tid & 3) * 8;
  short* As0 = &As[tid * 8];
  short* Bs0 = &Bs[tid * 8];

  for (int k0 = 0; k0 < K; k0 += 32) {
    uint4  a0 = *(const uint4*)(Ag + k0);
    uint4  a1 = *(const uint4*)(Ag + (size_t)64 * K + k0);
    float4 f0 = *(const float4*)(Bg + k0);
    float4 f1 = *(const float4*)(Bg + k0 + 4);
    float4 f2 = *(const float4*)(Bg + (size_t)64 * K + k0);
    float4 f3 = *(const float4*)(Bg + (size_t)64 * K + k0 + 4);
    __syncthreads();                      // previous iter's frag reads done
    *(uint4*)As0 = a0;
    *(uint4*)(As0 + 2048) = a1;
    *(short8*)Bs0 = cvt8(f0, f1);
    *(short8*)(Bs0 + 2048) = cvt8(f2, f3);
    __syncthreads();                      // tiles visible

    short8 af[4], bfr[4];
    #pragma unroll
    for (int mi = 0; mi < 4; mi++)
      af[mi] = *(const short8*)&As[(wm + mi * 16 + l15) * 32 + q * 8];
    #pragma unroll
    for (int ni = 0; ni < 4; ni++)
      bfr[ni] = *(const short8*)&Bs[(wn + ni * 16 + l15) * 32 + q * 8];
    #pragma unroll
    for (int mi = 0; mi < 4; mi++)
      #pragma unroll
      for (int ni = 0; ni < 4; ni++)
        acc[mi][ni] = __builtin_amdgcn_mfma_f32_16x16x32_bf16(af[mi], bfr[ni], acc[mi][ni], 0, 0, 0);
  }

  // epilogue: D row = (lane>>4)*4 + reg, col = lane&15  [measured m89/m91]
  #pragma unroll
  for (int mi = 0; mi < 4; mi++) {
    #pragma unroll
    for (int r = 0; r < 4; r++) {
      size_t row = (size_t)(m0 + wm + mi * 16 + q * 4 + r);
      size_t base = row * (size_t)N + n0 + wn + l15;
      #pragma unroll
      for (int ni = 0; ni < 4; ni++) {
        float v = acc[mi][ni][r];
        if (OUT_BF16) ((short*)Cv)[base + ni * 16] = f2bf(v);
        else          ((float*)Cv)[base + ni * 16] = v;
      }
    }
  }
}

// ---- h = silu(g) * u, elementwise bf16 ----
__global__ void k_silu(const short* __restrict__ g, const short* __restrict__ u,
                       short* __restrict__ h)
{
  size_t idx = ((size_t)blockIdx.x * 256 + threadIdx.x) * 8;
  short8 gv = *(const short8*)(g + idx);
  short8 uv = *(const short8*)(u + idx);
  short8 hv;
  #pragma unroll
  for (int i = 0; i < 8; i++) {
    float gf = bf2f(gv[i]);
    float s = gf / (1.f + __expf(-gf));
    hv[i] = f2bf(s * bf2f(uv[i]));
  }
  *(short8*)(h + idx) = hv;
}

// ---- out += w0*routed[row0] + w1*routed[row1] ----
__global__ void k_add(float* __restrict__ out, const short* __restrict__ rout,
                      const int* __restrict__ tok_row, const float* __restrict__ top_w)
{
  int t = blockIdx.x, tid = threadIdx.x;
  int r0 = tok_row[2*t], r1 = tok_row[2*t+1];
  float w0 = top_w[2*t], w1 = top_w[2*t+1];
  size_t c = (size_t)tid * 8;
  short8 a = *(const short8*)(rout + (size_t)r0 * DHID + c);
  short8 b = *(const short8*)(rout + (size_t)r1 * DHID + c);
  float* o = out + (size_t)t * DHID + c;
  float4 o0 = *(float4*)o;
  float4 o1 = *(float4*)(o + 4);
  o0.x += w0*bf2f(a[0]) + w1*bf2f(b[0]);
  o0.y += w0*bf2f(a[1]) + w1*bf2f(b[1]);
  o0.z += w0*bf2f(a[2]) + w1*bf2f(b[2]);
  o0.w += w0*bf2f(a[3]) + w1*bf2f(b[3]);
  o1.x += w0*bf2f(a[4]) + w1*bf2f(b[4]);
  o1.y += w0*bf2f(a[5]) + w1*bf2f(b[5]);
  o1.z += w0*bf2f(a[6]) + w1*bf2f(b[6]);
  o1.w += w0*bf2f(a[7]) + w1*bf2f(b[7]);
  *(float4*)o = o0;
  *(float4*)(o + 4) = o1;
}

extern "C" void kernel_launch(void* const* d_in, const int* in_sizes, int n_in,
                              void* d_out, int out_size, void* d_ws, size_t ws_size,
                              hipStream_t stream)
{
  const float* x   = (const float*)d_in[0];
  const float* gw  = (const float*)d_in[1];
  const float* swg = (const float*)d_in[2];
  const float* swu = (const float*)d_in[3];
  const float* swd = (const float*)d_in[4];
  const float* ewg = (const float*)d_in[5];
  const float* ewu = (const float*)d_in[6];
  const float* ewd = (const float*)d_in[7];
  float* out = (float*)d_out;

  // workspace carve (~94 MB)
  char* p = (char*)d_ws;
  int*   ctrl    = (int*)p;   p += 256;   // [0..7] counts, [8..15] cursor, [16..23] offsets
  int*   top_idx = (int*)p;   p += T_TOK * 2 * sizeof(int);
  float* top_w   = (float*)p; p += T_TOK * 2 * sizeof(float);
  int*   tok_row = (int*)p;   p += T_TOK * 2 * sizeof(int);
  short* x16  = (short*)p;    p += (size_t)T_TOK * DHID * 2;
  short* Xg   = (short*)p;    p += (size_t)CAP * DHID * 2;
  const size_t GU = (size_t)CAP * FMOE;   // >= T_TOK*FSH
  short* gbuf = (short*)p;    p += GU * 2;
  short* ubuf = (short*)p;    p += GU * 2;
  short* hbuf = (short*)p;    p += GU * 2;
  short* rout = (short*)p;    p += (size_t)CAP * DHID * 2;

  (void)hipMemsetAsync(ctrl, 0, 64, stream);   // counts + cursors

  k_gate<<<T_TOK, 256, 0, stream>>>(x, gw, top_idx, top_w, ctrl, x16);
  k_offsets<<<1, 64, 0, stream>>>(ctrl);
  k_gather<<<T_TOK, 256, 0, stream>>>(x16, top_idx, ctrl, tok_row, Xg);

  // shared: g,u in one dispatch (z selects), then silu*mul, then down into d_out
  k_gemm<false, true, true><<<dim3(FSH/128, T_TOK/128, 2), 256, 0, stream>>>(
      x16, swg, swu, gbuf, ubuf, FSH, DHID, nullptr);
  k_silu<<<(T_TOK * FSH) / (256 * 8), 256, 0, stream>>>(gbuf, ubuf, hbuf);
  k_gemm<false, false, false><<<dim3(DHID/128, T_TOK/128, 1), 256, 0, stream>>>(
      hbuf, swd, nullptr, out, nullptr, DHID, FSH, nullptr);

  // experts: g,u (z = expert*2 + which), silu*mul, down into routed buffer
  k_gemm<true, true, true><<<dim3(FMOE/128, T_TOK/128, 2*NEXP), 256, 0, stream>>>(
      Xg, ewg, ewu, gbuf, ubuf, FMOE, DHID, ctrl);
  k_silu<<<(CAP * FMOE) / (256 * 8), 256, 0, stream>>>(gbuf, ubuf, hbuf);
  k_gemm<true, false, true><<<dim3(DHID/128, T_TOK/128, NEXP), 256, 0, stream>>>(
      hbuf, ewd, nullptr, rout, nullptr, DHID, FMOE, ctrl);

  k_add<<<T_TOK, 256, 0, stream>>>(out, rout, tok_row, top_w);
}